// Round 7
// baseline (34132.867 us; speedup 1.0000x reference)
//
#include <hip/hip_runtime.h>

typedef _Float16 h16;
typedef __attribute__((ext_vector_type(2))) _Float16 h16x2;
typedef __attribute__((ext_vector_type(4))) _Float16 h16x4;
typedef __attribute__((ext_vector_type(8))) _Float16 h16x8;
typedef __attribute__((ext_vector_type(4))) float    f32x4;
typedef unsigned long long u64;

constexpr int B_  = 16;
constexpr int T_  = 2048;
constexpr int D_  = 512;
constexpr int H_  = 512;
constexpr int O_  = 256;
constexpr int G4_ = 2048;           // 4*H
constexpr int BT_ = B_ * T_;
constexpr int CAP_SPIN = 1 << 17;   // poll cap (insurance only)

__device__ __forceinline__ float sigm(float x)   { return 1.f / (1.f + __expf(-x)); }
__device__ __forceinline__ float tanh_f(float x) { return 1.f - 2.f / (1.f + __expf(2.f * x)); }

__device__ __forceinline__ u64 ald(const u64* p) {
  return __hip_atomic_load(p, __ATOMIC_RELAXED, __HIP_MEMORY_SCOPE_AGENT);
}

// ---------------- prep: fp32 x -> fp16 X, mask bits, t_max ----------------
__global__ void k_prep_x(const float* __restrict__ x, h16* __restrict__ Xh,
                         unsigned* __restrict__ maskbits, unsigned* __restrict__ tmaxp) {
  const int row = blockIdx.x;              // b*T + t
  const int b = row >> 11, t = row & 2047;
  const float2* xr = (const float2*)(x + (size_t)row * D_);
  float2 v = xr[threadIdx.x];
  h16x2 hv = { (h16)v.x, (h16)v.y };
  *(h16x2*)(Xh + (size_t)row * D_ + threadIdx.x * 2) = hv;
  float s = v.x + v.y;
  #pragma unroll
  for (int off = 32; off > 0; off >>= 1) s += __shfl_down(s, off, 64);
  __shared__ float red[4];
  const int lane = threadIdx.x & 63, wv = threadIdx.x >> 6;
  if (lane == 0) red[wv] = s;
  __syncthreads();
  if (threadIdx.x == 0) {
    float tot = red[0] + red[1] + red[2] + red[3];
    if (tot != 0.f) {
      atomicOr(&maskbits[t], 1u << b);
      atomicMax(tmaxp, (unsigned)(t + 1));
    }
  }
}

// ---------------- fp32 -> fp16 convert (weights) ----------------
__global__ void k_cvt(const float* __restrict__ s, h16* __restrict__ d, int n4) {
  int i = blockIdx.x * 256 + threadIdx.x;
  if (i < n4) {
    f32x4 v = ((const f32x4*)s)[i];
    h16x4 o = { (h16)v.x, (h16)v.y, (h16)v.z, (h16)v.w };
    ((h16x4*)d)[i] = o;
  }
}

__global__ void k_bias(const float* __restrict__ a, const float* __restrict__ b,
                       float* __restrict__ o, int n) {
  int i = blockIdx.x * 256 + threadIdx.x;
  if (i < n) o[i] = a[i] + b[i];
}

// ---------------- GEMM: C[m][n] = sum_k A[m,k]*B[n,k] ----------------
__global__ __launch_bounds__(256, 2)
void k_gemm(const h16* __restrict__ A, const h16* __restrict__ Bm, h16* __restrict__ C,
            int M, int N, int K) {
  __shared__ h16 As[128 * 32];
  __shared__ h16 Bs[128 * 32];
  const int tiles_n = N >> 7;
  const int tm = blockIdx.x / tiles_n, tn = blockIdx.x % tiles_n;
  const int tid = threadIdx.x, lane = tid & 63, wv = tid >> 6;
  const int wm = (wv >> 1) * 64, wn = (wv & 1) * 64;
  const int ml = lane & 15, qd = lane >> 4;
  f32x4 acc[4][4] = {};
  const h16* Arow = A + (size_t)(tm * 128) * K;
  const h16* Brow = Bm + (size_t)(tn * 128) * K;
  for (int kt = 0; kt < K; kt += 32) {
    __syncthreads();
    #pragma unroll
    for (int p = 0; p < 2; ++p) {
      int ch = tid + p * 256;
      int r = ch >> 2, qq = ch & 3;
      int sidx = r * 4 + ((qq + r) & 3);
      *(h16x8*)(As + sidx * 8) = *(const h16x8*)(Arow + (size_t)r * K + kt + qq * 8);
      *(h16x8*)(Bs + sidx * 8) = *(const h16x8*)(Brow + (size_t)r * K + kt + qq * 8);
    }
    __syncthreads();
    h16x8 af[4], bfv[4];
    #pragma unroll
    for (int i = 0; i < 4; ++i) {
      int ra = wm + i * 16 + ml;
      af[i]  = *(const h16x8*)(As + (ra * 4 + ((qd + ra) & 3)) * 8);
      int rb = wn + i * 16 + ml;
      bfv[i] = *(const h16x8*)(Bs + (rb * 4 + ((qd + rb) & 3)) * 8);
    }
    #pragma unroll
    for (int i = 0; i < 4; ++i)
      #pragma unroll
      for (int j = 0; j < 4; ++j)
        acc[i][j] = __builtin_amdgcn_mfma_f32_16x16x32_f16(af[i], bfv[j], acc[i][j], 0, 0, 0);
  }
  const int colb = lane & 15, rowq = (lane >> 4) * 4;
  #pragma unroll
  for (int i = 0; i < 4; ++i)
    #pragma unroll
    for (int j = 0; j < 4; ++j) {
      int row0 = tm * 128 + wm + i * 16 + rowq;
      int col  = tn * 128 + wn + j * 16 + colb;
      #pragma unroll
      for (int r = 0; r < 4; ++r)
        C[(size_t)(row0 + r) * N + col] = (h16)acc[i][j][r];
    }
}

// ---------------- single-pipeline fused 2-layer recurrence ----------------
// 32 WGs, WG g owns cols [16g,16g+16) of BOTH layers. Rings R0/R1: tag-in-word
// u32 = (tag<<16)|fp16, 4 slots x [16 samples][512 cols]. Round r: A-part
// computes h0(r+1) (tag r+1, slot (r+1)&3); B-part computes h1(r) (tag r,
// slot r&3) from h0(r) and h1(r-1). Skew between WGs provably <=1 => depth-4
// rings can't overwrite live data. Lanes poll their own MFMA B-fragments
// directly from the ring (no LDS staging); h0 fragments reused for Whh0 and
// Wih1 MFMAs. 2 barriers/round; h0 publish right after the first one.
__global__ __launch_bounds__(256, 1)
void k_lstm3(const h16* __restrict__ G,
             const h16* __restrict__ Whh0,
             const h16* __restrict__ Wih1,
             const h16* __restrict__ Whh1,
             const float* __restrict__ bias0,
             const float* __restrict__ bias1,
             const unsigned* __restrict__ maskbits,
             const unsigned* __restrict__ tmaxp,
             unsigned* R0, unsigned* R1, float* hT_out) {
  const int g = blockIdx.x;
  const int tid = threadIdx.x, lane = tid & 63, w = tid >> 6;
  const int nl = lane & 15, qd = lane >> 4;

  __shared__ float gate0[4][16][17];
  __shared__ float gate1[4][16][17];
  __shared__ float c0s[16][16], c1s[16][16];
  __shared__ float h0c[16][16], h1c[16][16];

  // resident weights: rows w*512 + g*16 + nl, k = kt*32 + qd*8 + j
  h16x8 a0[16], ai[16], a1[16];
  {
    const h16* p = Whh0 + (size_t)(w * 512 + g * 16 + nl) * 512 + qd * 8;
    #pragma unroll
    for (int kt = 0; kt < 16; ++kt) a0[kt] = *(const h16x8*)(p + kt * 32);
  }
  {
    const h16* p = Wih1 + (size_t)(w * 512 + g * 16 + nl) * 512 + qd * 8;
    #pragma unroll
    for (int kt = 0; kt < 16; ++kt) ai[kt] = *(const h16x8*)(p + kt * 32);
  }
  {
    const h16* p = Whh1 + (size_t)(w * 512 + g * 16 + nl) * 512 + qd * 8;
    #pragma unroll
    for (int kt = 0; kt < 16; ++kt) a1[kt] = *(const h16x8*)(p + kt * 32);
  }
  float b0v[4], b1v[4];
  #pragma unroll
  for (int r = 0; r < 4; ++r) {
    b0v[r] = bias0[w * 512 + g * 16 + qd * 4 + r];
    b1v[r] = bias1[w * 512 + g * 16 + qd * 4 + r];
  }

  { int jj = tid >> 4, n = tid & 15;
    c0s[jj][n] = 0.f; c1s[jj][n] = 0.f; h0c[jj][n] = 0.f; h1c[jj][n] = 0.f; }
  __syncthreads();

  unsigned Su = *tmaxp;
  if (Su < 1u) Su = 1u;
  if (Su > (unsigned)T_) Su = (unsigned)T_;
  const int S = (int)Su;

  h16x4 gv_cur = *(const h16x4*)(G + ((size_t)nl * T_ + 0) * G4_ + w * 512 + g * 16 + qd * 4);

  for (int r = 0; r <= S; ++r) {
    const bool doA = (r < S), doB = (r >= 1), haveH0 = (r >= 1), haveH1 = (r >= 2);

    // prefetch next-round x-gates
    h16x4 gv_next;
    { int tn = (r + 1 < S) ? (r + 1) : 0;
      gv_next = *(const h16x4*)(G + ((size_t)nl * T_ + tn) * G4_ + w * 512 + g * 16 + qd * 4); }

    // ---- poll h0(r) fragments straight into registers ----
    h16x8 b0f[16];
    if (haveH0) {
      const u64 expw = ((u64)(unsigned)r << 16) | ((u64)(unsigned)r << 48);
      const u64* bp = (const u64*)R0 + ((size_t)(r & 3) * 16 + nl) * 256 + qd * 4;
      u64 w0[16][4];
      #pragma unroll
      for (int kt = 0; kt < 16; ++kt)
        #pragma unroll
        for (int i = 0; i < 4; ++i) w0[kt][i] = ald(bp + kt * 16 + i);
      for (int it = 0; it < CAP_SPIN; ++it) {
        unsigned bad = 0;
        #pragma unroll
        for (int kt = 0; kt < 16; ++kt) {
          bool ok = true;
          #pragma unroll
          for (int i = 0; i < 4; ++i)
            ok &= ((w0[kt][i] & 0xFFFF0000FFFF0000ull) == expw);
          bad |= ok ? 0u : (1u << kt);
        }
        if (!bad) break;
        #pragma unroll
        for (int kt = 0; kt < 16; ++kt)
          if (bad & (1u << kt))
            #pragma unroll
            for (int i = 0; i < 4; ++i) w0[kt][i] = ald(bp + kt * 16 + i);
      }
      #pragma unroll
      for (int kt = 0; kt < 16; ++kt) {
        union { unsigned u[4]; h16x8 f; } cv;
        #pragma unroll
        for (int i = 0; i < 4; ++i) {
          u64 v = w0[kt][i];
          cv.u[i] = (unsigned)(v & 0xffffull) | (((unsigned)(v >> 32) & 0xffffu) << 16);
        }
        b0f[kt] = cv.f;
      }
    }

    // ---- L0: gates + activations ----
    if (doA) {
      f32x4 acc0 = {0.f, 0.f, 0.f, 0.f};
      if (haveH0) {
        #pragma unroll
        for (int kt = 0; kt < 16; ++kt)
          acc0 = __builtin_amdgcn_mfma_f32_16x16x32_f16(a0[kt], b0f[kt], acc0, 0, 0, 0);
      }
      #pragma unroll
      for (int rr = 0; rr < 4; ++rr) {
        float pre = acc0[rr] + b0v[rr] + (float)gv_cur[rr];
        gate0[w][qd * 4 + rr][nl] = (w == 2) ? tanh_f(pre) : sigm(pre);
      }
    }
    gv_cur = gv_next;
    __syncthreads();                       // gate0 complete

    // ---- cell0 + IMMEDIATE h0(r+1) publish (critical path ends here) ----
    if (doA && tid < 128) {
      const int n = tid >> 3, j = (tid & 7) * 2;
      const unsigned mw = maskbits[r];
      const bool msk = (mw >> n) & 1u;
      unsigned pw[2];
      #pragma unroll
      for (int u = 0; u < 2; ++u) {
        const int jj = j + u;
        float iv = gate0[0][jj][n], fv = gate0[1][jj][n];
        float gg = gate0[2][jj][n], ov = gate0[3][jj][n];
        float c_old = c0s[jj][n];
        float c_new = msk ? (fv * c_old + iv * gg) : c_old;
        float h_new = msk ? (ov * tanh_f(c_new)) : h0c[jj][n];
        c0s[jj][n] = c_new; h0c[jj][n] = h_new;
        h16 hh = (h16)h_new;
        unsigned short hb; __builtin_memcpy(&hb, &hh, 2);
        pw[u] = ((unsigned)(r + 1) << 16) | (unsigned)hb;
      }
      u64 pv = (u64)pw[0] | ((u64)pw[1] << 32);
      u64* wp = (u64*)R0 + ((size_t)((r + 1) & 3) * 16 + n) * 256 + (g * 16 + j) / 2;
      __hip_atomic_store(wp, pv, __ATOMIC_RELAXED, __HIP_MEMORY_SCOPE_AGENT);
    }

    // ---- L1: runs entirely in the RTT shadow ----
    if (doB) {
      f32x4 acc1 = {0.f, 0.f, 0.f, 0.f};
      #pragma unroll
      for (int kt = 0; kt < 16; ++kt)
        acc1 = __builtin_amdgcn_mfma_f32_16x16x32_f16(ai[kt], b0f[kt], acc1, 0, 0, 0);
      if (haveH1) {
        const u64 expw = ((u64)(unsigned)(r - 1) << 16) | ((u64)(unsigned)(r - 1) << 48);
        const u64* bp = (const u64*)R1 + ((size_t)((r - 1) & 3) * 16 + nl) * 256 + qd * 4;
        #pragma unroll
        for (int half = 0; half < 2; ++half) {
          u64 w1[8][4];
          #pragma unroll
          for (int k2 = 0; k2 < 8; ++k2)
            #pragma unroll
            for (int i = 0; i < 4; ++i) w1[k2][i] = ald(bp + (half * 8 + k2) * 16 + i);
          for (int it = 0; it < CAP_SPIN; ++it) {
            unsigned bad = 0;
            #pragma unroll
            for (int k2 = 0; k2 < 8; ++k2) {
              bool ok = true;
              #pragma unroll
              for (int i = 0; i < 4; ++i)
                ok &= ((w1[k2][i] & 0xFFFF0000FFFF0000ull) == expw);
              bad |= ok ? 0u : (1u << k2);
            }
            if (!bad) break;
            #pragma unroll
            for (int k2 = 0; k2 < 8; ++k2)
              if (bad & (1u << k2))
                #pragma unroll
                for (int i = 0; i < 4; ++i) w1[k2][i] = ald(bp + (half * 8 + k2) * 16 + i);
          }
          #pragma unroll
          for (int k2 = 0; k2 < 8; ++k2) {
            union { unsigned u[4]; h16x8 f; } cv;
            #pragma unroll
            for (int i = 0; i < 4; ++i) {
              u64 v = w1[k2][i];
              cv.u[i] = (unsigned)(v & 0xffffull) | (((unsigned)(v >> 32) & 0xffffu) << 16);
            }
            acc1 = __builtin_amdgcn_mfma_f32_16x16x32_f16(a1[half * 8 + k2], cv.f, acc1, 0, 0, 0);
          }
        }
      }
      #pragma unroll
      for (int rr = 0; rr < 4; ++rr) {
        float pre = acc1[rr] + b1v[rr];
        gate1[w][qd * 4 + rr][nl] = (w == 2) ? tanh_f(pre) : sigm(pre);
      }
    }
    __syncthreads();                       // gate1 complete; gate0 consumed

    // ---- cell1 + h1(r) publish ----
    if (doB && tid >= 128) {
      const int t2 = tid - 128;
      const int n = t2 >> 3, j = (t2 & 7) * 2;
      const unsigned mw = maskbits[r - 1];
      const bool msk = (mw >> n) & 1u;
      unsigned pw[2];
      #pragma unroll
      for (int u = 0; u < 2; ++u) {
        const int jj = j + u;
        float iv = gate1[0][jj][n], fv = gate1[1][jj][n];
        float gg = gate1[2][jj][n], ov = gate1[3][jj][n];
        float c_old = c1s[jj][n];
        float c_new = msk ? (fv * c_old + iv * gg) : c_old;
        float h_new = msk ? (ov * tanh_f(c_new)) : h1c[jj][n];
        c1s[jj][n] = c_new; h1c[jj][n] = h_new;
        h16 hh = (h16)h_new;
        unsigned short hb; __builtin_memcpy(&hb, &hh, 2);
        pw[u] = ((unsigned)r << 16) | (unsigned)hb;
      }
      u64 pv = (u64)pw[0] | ((u64)pw[1] << 32);
      u64* wp = (u64*)R1 + ((size_t)(r & 3) * 16 + n) * 256 + (g * 16 + j) / 2;
      __hip_atomic_store(wp, pv, __ATOMIC_RELAXED, __HIP_MEMORY_SCOPE_AGENT);
    }
  }

  __syncthreads();
  { const int n = tid >> 4, jj = tid & 15;
    hT_out[n * H_ + g * 16 + jj] = h1c[jj][n]; }
}

// ---------------- final FC ----------------
__global__ void k_fc(const float* __restrict__ hT, const float* __restrict__ Wfc,
                     const float* __restrict__ bfc, float* __restrict__ out) {
  const int b = blockIdx.x;
  __shared__ float hs[H_];
  for (int i = threadIdx.x; i < H_; i += 256) hs[i] = hT[(size_t)b * H_ + i];
  __syncthreads();
  const int o = threadIdx.x;
  const float* wr = Wfc + (size_t)o * H_;
  float s = bfc[o];
  for (int k = 0; k < H_; k += 4) {
    f32x4 w4 = *(const f32x4*)(wr + k);
    s += hs[k] * w4.x + hs[k + 1] * w4.y + hs[k + 2] * w4.z + hs[k + 3] * w4.w;
  }
  out[(size_t)b * O_ + o] = s;
}

extern "C" void kernel_launch(void* const* d_in, const int* in_sizes, int n_in,
                              void* d_out, int out_size, void* d_ws, size_t ws_size,
                              hipStream_t stream) {
  const float* x    = (const float*)d_in[0];
  const float* Wih0 = (const float*)d_in[1];
  const float* Whh0 = (const float*)d_in[2];
  const float* bih0 = (const float*)d_in[3];
  const float* bhh0 = (const float*)d_in[4];
  const float* Wih1 = (const float*)d_in[5];
  const float* Whh1 = (const float*)d_in[6];
  const float* bih1 = (const float*)d_in[7];
  const float* bhh1 = (const float*)d_in[8];
  const float* Wfc  = (const float*)d_in[9];
  const float* bfc  = (const float*)d_in[10];

  char* base = (char*)d_ws;
  size_t off = 0;
  auto alloc = [&](size_t bytes) -> void* {
    void* r = base + off;
    off = (off + bytes + 255) & ~(size_t)255;
    return r;
  };
  h16* Xh   = (h16*)alloc((size_t)BT_ * D_ * 2);
  h16* Gbuf = (h16*)alloc((size_t)BT_ * G4_ * 2);
  h16* Wb0  = (h16*)alloc((size_t)G4_ * D_ * 2);
  h16* Wb1  = (h16*)alloc((size_t)G4_ * H_ * 2);   // Whh0
  h16* Wb2  = (h16*)alloc((size_t)G4_ * H_ * 2);   // Wih1
  h16* Wb3  = (h16*)alloc((size_t)G4_ * H_ * 2);   // Whh1
  float* bs0 = (float*)alloc(G4_ * 4);
  float* bs1 = (float*)alloc(G4_ * 4);
  unsigned* maskbits = (unsigned*)alloc(T_ * 4);
  unsigned* tmaxp    = (unsigned*)alloc(256);
  unsigned* R0 = (unsigned*)alloc((size_t)4 * 16 * 512 * 4);
  unsigned* R1 = (unsigned*)alloc((size_t)4 * 16 * 512 * 4);
  float* hT = (float*)alloc((size_t)B_ * H_ * 4);

  hipMemsetAsync(maskbits, 0, T_ * 4, stream);
  hipMemsetAsync(tmaxp, 0, 256, stream);
  hipMemsetAsync(R0, 0, (size_t)4 * 16 * 512 * 4, stream);
  hipMemsetAsync(R1, 0, (size_t)4 * 16 * 512 * 4, stream);
  k_prep_x<<<BT_, 256, 0, stream>>>(x, Xh, maskbits, tmaxp);
  const int wn4 = G4_ * D_ / 4;
  k_cvt<<<(wn4 + 255) / 256, 256, 0, stream>>>(Wih0, Wb0, wn4);
  k_cvt<<<(wn4 + 255) / 256, 256, 0, stream>>>(Whh0, Wb1, wn4);
  k_cvt<<<(wn4 + 255) / 256, 256, 0, stream>>>(Wih1, Wb2, wn4);
  k_cvt<<<(wn4 + 255) / 256, 256, 0, stream>>>(Whh1, Wb3, wn4);
  k_bias<<<(G4_ + 255) / 256, 256, 0, stream>>>(bih0, bhh0, bs0, G4_);
  k_bias<<<(G4_ + 255) / 256, 256, 0, stream>>>(bih1, bhh1, bs1, G4_);

  k_gemm<<<(BT_ / 128) * (G4_ / 128), 256, 0, stream>>>(Xh, Wb0, Gbuf, BT_, G4_, D_);
  k_lstm3<<<32, 256, 0, stream>>>(Gbuf, Wb1, Wb2, Wb3, bs0, bs1, maskbits, tmaxp,
                                  R0, R1, hT);
  k_fc<<<B_, 256, 0, stream>>>(hT, Wfc, bfc, (float*)d_out);
}